// Round 4
// baseline (7058.041 us; speedup 1.0000x reference)
//
#include <hip/hip_runtime.h>
#include <cstdint>
#include <cstddef>

typedef unsigned int UINT;
typedef unsigned short USHORT;

// ---------- constants ----------
// B=32 S=128 V=32000 NT=64 NE=100 H=400 NL=128 NM=100
#define TOKENS 4096      // B*S
#define HID 400
#define G4 1600          // 4*H
#define SEQ 128
#define NB 32
#define NPOS 127         // S-1
#define NROW 4064        // B*NPOS
#define LD1T 4064
#define CHUNK_B 4        // batches per biaffine/transpose chunk

typedef _Float16 h2f __attribute__((ext_vector_type(2)));

__device__ __forceinline__ float dot2f(UINT w, UINT h, float acc){
#if __has_builtin(__builtin_amdgcn_fdot2)
    return __builtin_amdgcn_fdot2(__builtin_bit_cast(h2f, w), __builtin_bit_cast(h2f, h), acc, false);
#else
    h2f a = __builtin_bit_cast(h2f, w); h2f b = __builtin_bit_cast(h2f, h);
    return acc + (float)a.x * (float)b.x + (float)a.y * (float)b.y;
#endif
}

__device__ __forceinline__ float sigm(float x){ return 1.f / (1.f + __expf(-x)); }
__device__ __forceinline__ float tanh_f(float x){ float e = __expf(2.f * x); return (e - 1.f) / (e + 1.f); }

// ---------- 1) Whh (3,2,1600,400) f32 -> f16 k-pair-packed, gate-interleaved ----------
__global__ __launch_bounds__(256) void k_convert_whh(const float* __restrict__ whh, UINT* __restrict__ wpk){
    int idx = blockIdx.x * 256 + threadIdx.x;      // 0 .. 479,999
    if (idx >= 480000) return;
    int ld_i = idx / 80000;                        // layer*2+dir
    int rem  = idx % 80000;
    int k2 = rem / 400;
    int j  = rem % 400;
    const float* srcb = whh + (size_t)ld_i * G4 * HID + 2 * k2;
    UINT p[4];
    #pragma unroll
    for (int g = 0; g < 4; g++){
        const float* src = srcb + (size_t)(g * HID + j) * HID;
        _Float16 w0 = (_Float16)src[0];
        _Float16 w1 = (_Float16)src[1];
        p[g] = (UINT)__builtin_bit_cast(USHORT, w0) | ((UINT)__builtin_bit_cast(USHORT, w1) << 16);
    }
    uint4 v; v.x = p[0]; v.y = p[1]; v.z = p[2]; v.w = p[3];
    ((uint4*)wpk)[(size_t)ld_i * 80000 + (size_t)k2 * 400 + j] = v;
}

// ---------- 2) embedding concat -> x (4096 x 200) fp32 ----------
__global__ __launch_bounds__(64) void k_embed(const int* __restrict__ words, const int* __restrict__ tags,
                                              const float* __restrict__ wemb, const float* __restrict__ temb,
                                              float* __restrict__ xA){
    int tok = blockIdx.x;
    int w = words[tok], tg = tags[tok];
    float* dst = xA + (size_t)tok * 200;
    for (int i = threadIdx.x; i < 100; i += 64){
        dst[i]       = wemb[(size_t)w * 100 + i];
        dst[100 + i] = temb[(size_t)tg * 100 + i];
    }
}

// ---------- 3) input projection GEMM ----------
__global__ __launch_bounds__(256) void k_gemm_ih(const float* __restrict__ X, int ldX, int K,
                                                 const float* __restrict__ Wih, const float* __restrict__ bias,
                                                 _Float16* __restrict__ Zh){
    int dir = blockIdx.z;
    int o0 = blockIdx.x * 64, tok0 = blockIdx.y * 64;
    const float* W  = Wih + (size_t)dir * G4 * K;
    const float* bb = bias + dir * G4;
    _Float16* Zd = Zh + (size_t)dir * TOKENS * G4;
    __shared__ float Xs[16][68];
    __shared__ float Ws[16][68];
    int tid = threadIdx.x;
    int tx = tid & 15, ty = tid >> 4;
    float acc[4][4];
    #pragma unroll
    for (int j = 0; j < 4; j++){
        float bv = bb[o0 + tx * 4 + j];
        #pragma unroll
        for (int i = 0; i < 4; i++) acc[i][j] = bv;
    }
    int lr = tid >> 2;          // 0..63
    int lc = (tid & 3) * 4;     // 0,4,8,12
    for (int k0 = 0; k0 < K; k0 += 16){
        float4 xv = {0.f,0.f,0.f,0.f};
        float4 wv = {0.f,0.f,0.f,0.f};
        if (k0 + lc < K){
            xv = *(const float4*)(X + (size_t)(tok0 + lr) * ldX + k0 + lc);
            wv = *(const float4*)(W + (size_t)(o0 + lr) * K + k0 + lc);
        }
        __syncthreads();
        Xs[lc+0][lr] = xv.x; Xs[lc+1][lr] = xv.y; Xs[lc+2][lr] = xv.z; Xs[lc+3][lr] = xv.w;
        Ws[lc+0][lr] = wv.x; Ws[lc+1][lr] = wv.y; Ws[lc+2][lr] = wv.z; Ws[lc+3][lr] = wv.w;
        __syncthreads();
        #pragma unroll
        for (int kk = 0; kk < 16; kk++){
            float4 a = *(const float4*)&Xs[kk][ty * 4];
            float4 w = *(const float4*)&Ws[kk][tx * 4];
            float av[4] = {a.x, a.y, a.z, a.w};
            float wv2[4] = {w.x, w.y, w.z, w.w};
            #pragma unroll
            for (int i = 0; i < 4; i++)
                #pragma unroll
                for (int j = 0; j < 4; j++)
                    acc[i][j] += av[i] * wv2[j];
        }
    }
    #pragma unroll
    for (int i = 0; i < 4; i++){
        _Float16* zr = Zd + (size_t)(tok0 + ty * 4 + i) * G4 + o0 + tx * 4;
        #pragma unroll
        for (int j = 0; j < 4; j++) zr[j] = (_Float16)acc[i][j];
    }
}

// ---------- 4) LSTM recurrence: one block per (batch, dir) chain; split-K over 2 halves ----------
// 1024 threads: (kh = tid>>9, j = tid&511, active j<400). Each half does 100 dwordx4 loads/step,
// partials combined in LDS by kh=0 threads. 16 waves/CU for latency hiding.
__global__ __launch_bounds__(1024) void k_lstm(const _Float16* __restrict__ Zh, const UINT* __restrict__ wpk,
                                               float* __restrict__ Xout, int layer){
    int bi = blockIdx.x >> 1, dir = blockIdx.x & 1;
    const uint4* wp4 = (const uint4*)wpk + (size_t)(layer * 2 + dir) * 80000;
    const _Float16* Zd = Zh + (size_t)dir * TOKENS * G4 + (size_t)bi * SEQ * G4;
    float* Xo = Xout + (size_t)bi * SEQ * 800 + dir * HID;
    __shared__ __align__(16) _Float16 hsh[HID];
    __shared__ __align__(16) float ps[2][HID][4];    // [kh][j][gate]
    UINT* hu = (UINT*)hsh;
    int tid = threadIdx.x;
    int kh = tid >> 9;          // 0 or 1
    int j  = tid & 511;         // 0..511
    bool act = (j < HID);
    if (tid < 200) hu[tid] = 0u;
    float c = 0.f;
    __syncthreads();
    for (int s = 0; s < SEQ; s++){
        int t = dir ? (SEQ - 1 - s) : s;
        if (act){
            float a0, a1, a2, a3;
            if (kh == 0){
                const _Float16* zr = Zd + (size_t)t * G4;
                a0 = (float)zr[j]; a1 = (float)zr[HID + j];
                a2 = (float)zr[2*HID + j]; a3 = (float)zr[3*HID + j];
            } else { a0 = a1 = a2 = a3 = 0.f; }
            const uint4* w0 = wp4 + (size_t)(kh * 100) * 400 + j;
            const UINT* hub = hu + kh * 100;
            #pragma unroll 8
            for (int k2 = 0; k2 < 100; k2++){
                UINT hp = hub[k2];
                uint4 w = w0[(size_t)k2 * 400];
                a0 = dot2f(w.x, hp, a0);
                a1 = dot2f(w.y, hp, a1);
                a2 = dot2f(w.z, hp, a2);
                a3 = dot2f(w.w, hp, a3);
            }
            float4 p; p.x = a0; p.y = a1; p.z = a2; p.w = a3;
            *(float4*)&ps[kh][j][0] = p;
        }
        __syncthreads();
        if (act && kh == 0){
            float4 p0 = *(const float4*)&ps[0][j][0];
            float4 p1 = *(const float4*)&ps[1][j][0];
            float ai = p0.x + p1.x, af = p0.y + p1.y;
            float ag = p0.z + p1.z, ao = p0.w + p1.w;
            float ig = sigm(ai), fg = sigm(af), gg = tanh_f(ag), og = sigm(ao);
            c = fg * c + ig * gg;
            float hval = og * tanh_f(c);
            Xo[(size_t)t * 800 + j] = hval;
            hsh[j] = (_Float16)hval;
        }
        __syncthreads();
    }
}

// ---------- 5) MLPs -> transposed l1T/r1T [feature][row] ----------
__global__ __launch_bounds__(256) void k_mlp(const float* __restrict__ X,
                                             const float* __restrict__ Wl, const float* __restrict__ bl,
                                             const float* __restrict__ Wr, const float* __restrict__ br,
                                             float* __restrict__ l1T, float* __restrict__ r1T){
    int r = blockIdx.x;            // 0..4063
    int b = r / NPOS, x = r % NPOS;
    __shared__ float feat[800];
    const float* xrow = X + (size_t)(b * SEQ + x) * 800;
    int tid = threadIdx.x;
    for (int k = tid; k < 800; k += 256) feat[k] = (k < 400) ? xrow[k] : xrow[800 + k];
    __syncthreads();
    if (tid < 200){
        int isl = (tid < 100);
        int m = isl ? tid : tid - 100;
        const float* W = (isl ? Wl : Wr) + (size_t)m * 800;
        float acc = (isl ? bl : br)[m];
        for (int k = 0; k < 800; k += 4){
            float4 w4 = *(const float4*)(W + k);
            acc += w4.x * feat[k]   + w4.y * feat[k+1]
                 + w4.z * feat[k+2] + w4.w * feat[k+3];
        }
        float v = acc > 0.f ? acc : 0.1f * acc;
        (isl ? l1T : r1T)[(size_t)m * LD1T + r] = v;
    } else if (tid == 200){ l1T[(size_t)100 * LD1T + r] = 1.0f; }
    else if (tid == 201){ r1T[(size_t)100 * LD1T + r] = 1.0f; }
}

// ---------- 6a) biaffine -> T[bb][o][x][ypad128], coalesced stores ----------
__global__ __launch_bounds__(256) void k_biaffineT(const float* __restrict__ l1T, const float* __restrict__ r1T,
                                                   const float* __restrict__ BW, float* __restrict__ T, int b0){
    int o = blockIdx.x, bb = blockIdx.y, b = b0 + bb;
    extern __shared__ float sm[];
    float* Wl = sm;                  // 101*104
    float* Rt = sm + 101 * 104;      // 101*128
    float* Vt = Rt + 101 * 128;      // 101*128
    float* Lt = sm;                  // reuse after stage A
    int tid = threadIdx.x;
    const float* wo = BW + (size_t)o * 10201;
    for (int idx = tid; idx < 10201; idx += 256){
        int i = idx / 101, jj = idx % 101;
        Wl[i * 104 + jj] = wo[idx];
    }
    const float* rb = r1T + b * NPOS;
    for (int idx = tid; idx < 101 * 128; idx += 256){
        int jj = idx >> 7, y = idx & 127;
        Rt[idx] = (y < NPOS) ? rb[(size_t)jj * LD1T + y] : 0.f;
    }
    __syncthreads();
    {   // stage A: Vt[i][y] = sum_j Wl[i][j] * Rt[j][y]
        int ty = tid & 31, ti = tid >> 5;
        for (int i = ti; i < 101; i += 8){
            float a0 = 0.f, a1 = 0.f, a2 = 0.f, a3 = 0.f;
            const float* wrow = Wl + i * 104;
            #pragma unroll 2
            for (int jj = 0; jj < 101; jj++){
                float w = wrow[jj];
                float4 r4 = *(const float4*)(Rt + jj * 128 + ty * 4);
                a0 += w * r4.x; a1 += w * r4.y; a2 += w * r4.z; a3 += w * r4.w;
            }
            float4 v; v.x = a0; v.y = a1; v.z = a2; v.w = a3;
            *(float4*)(Vt + i * 128 + ty * 4) = v;
        }
    }
    __syncthreads();
    const float* lb = l1T + b * NPOS;
    for (int idx = tid; idx < 101 * 128; idx += 256){
        int ii = idx >> 7, x = idx & 127;
        Lt[idx] = (x < NPOS) ? lb[(size_t)ii * LD1T + x] : 0.f;
    }
    __syncthreads();
    {   // stage B: S[x][y] = sum_i Lt[i][x] * Vt[i][y]; lanes vary y -> coalesced T stores
        int ty = tid & 31;
        int tx8 = tid >> 5;
        float* tb = T + (size_t)(bb * 128 + o) * 127 * 128;
        for (int xp = 0; xp < 4; xp++){
            int x0 = (tx8 + 8 * xp) * 4;
            float accm[4][4] = {};   // [xx][yy]
            for (int i = 0; i < 101; i++){
                float4 l4 = *(const float4*)(Lt + i * 128 + x0);
                float4 v4 = *(const float4*)(Vt + i * 128 + ty * 4);
                float lv[4] = {l4.x, l4.y, l4.z, l4.w};
                float vv[4] = {v4.x, v4.y, v4.z, v4.w};
                #pragma unroll
                for (int xx = 0; xx < 4; xx++)
                    #pragma unroll
                    for (int yy = 0; yy < 4; yy++)
                        accm[xx][yy] += lv[xx] * vv[yy];
            }
            #pragma unroll
            for (int xx = 0; xx < 4; xx++){
                int x = x0 + xx;
                if (x >= NPOS) continue;
                float4 w; w.x = accm[xx][0]; w.y = accm[xx][1]; w.z = accm[xx][2]; w.w = accm[xx][3];
                *(float4*)(tb + (size_t)x * 128 + ty * 4) = w;
            }
        }
    }
}

// ---------- 6b) transpose T[bb][o][x][ypad] -> out[b][x][y][o] ----------
__global__ __launch_bounds__(256) void k_transpose(const float* __restrict__ T, float* __restrict__ out, int b0){
    int x = blockIdx.x, bb = blockIdx.y, b = b0 + bb;
    extern __shared__ float ts[];    // [o][129]
    int tid = threadIdx.x;
    for (int idx = tid; idx < 128 * 32; idx += 256){
        int o = idx >> 5, y4 = idx & 31;
        float4 v = *(const float4*)(T + ((size_t)(bb * 128 + o) * 127 + x) * 128 + y4 * 4);
        float* d = ts + o * 129 + y4 * 4;
        d[0] = v.x; d[1] = v.y; d[2] = v.z; d[3] = v.w;
    }
    __syncthreads();
    float* ob = out + ((size_t)(b * NPOS + x)) * NPOS * 128;
    for (int idx = tid; idx < NPOS * 32; idx += 256){
        int y = idx >> 5, o4 = idx & 31;
        float4 w;
        w.x = ts[(o4 * 4 + 0) * 129 + y];
        w.y = ts[(o4 * 4 + 1) * 129 + y];
        w.z = ts[(o4 * 4 + 2) * 129 + y];
        w.w = ts[(o4 * 4 + 3) * 129 + y];
        *(float4*)(ob + (size_t)y * 128 + o4 * 4) = w;
    }
}

extern "C" void kernel_launch(void* const* d_in, const int* in_sizes, int n_in,
                              void* d_out, int out_size, void* d_ws, size_t ws_size,
                              hipStream_t stream) {
    const int* words = (const int*)d_in[0];
    const int* tags  = (const int*)d_in[1];
    const float* wemb = (const float*)d_in[2];
    const float* temb = (const float*)d_in[3];
    const float* wih[3] = {(const float*)d_in[4], (const float*)d_in[5], (const float*)d_in[6]};
    const float* whh  = (const float*)d_in[7];
    const float* bias = (const float*)d_in[8];
    const float* mlW = (const float*)d_in[9];
    const float* mlb = (const float*)d_in[10];
    const float* mrW = (const float*)d_in[11];
    const float* mrb = (const float*)d_in[12];
    const float* bw  = (const float*)d_in[13];
    float* out = (float*)d_out;

    // workspace layout (bytes):
    //   [0 .. 13,107,200)            x f32 (reused as T after k_mlp)
    //   [13,107,200 .. 39,321,600)   Zh f16 (T overlaps this region too during biaffine)
    //   [39,321,600 .. 47,001,600)   wpk u32 during LSTM; l1T/r1T live here after last LSTM
    char* base = (char*)d_ws;
    float*     x   = (float*)base;
    _Float16*  Zh  = (_Float16*)(base + 13107200);
    UINT*      wpk = (UINT*)(base + 13107200 + 26214400);
    float*     l1T = (float*)(base + 39321600);
    float*     r1T = l1T + (size_t)104 * LD1T;
    float*     T   = (float*)base;

    k_convert_whh<<<1875, 256, 0, stream>>>(whh, wpk);
    k_embed<<<TOKENS, 64, 0, stream>>>(words, tags, wemb, temb, x);

    for (int l = 0; l < 3; l++){
        int K = l ? 800 : 200;
        k_gemm_ih<<<dim3(25, 64, 2), 256, 0, stream>>>(x, K, K, wih[l], bias + l * 2 * G4, Zh);
        k_lstm<<<64, 1024, 0, stream>>>(Zh, wpk, x, l);
    }
    k_mlp<<<NROW, 256, 0, stream>>>(x, mlW, mlb, mrW, mrb, l1T, r1T);

    (void)hipFuncSetAttribute((const void*)k_biaffineT, hipFuncAttributeMaxDynamicSharedMemorySize, 145440);
    (void)hipFuncSetAttribute((const void*)k_transpose, hipFuncAttributeMaxDynamicSharedMemorySize, 66048);
    for (int c = 0; c < NB / CHUNK_B; c++){
        k_biaffineT<<<dim3(128, CHUNK_B), 256, 145440, stream>>>(l1T, r1T, bw, T, c * CHUNK_B);
        k_transpose<<<dim3(NPOS, CHUNK_B), 256, 66048, stream>>>(T, out, c * CHUNK_B);
    }
}

// Round 5
// 6966.737 us; speedup vs baseline: 1.0131x; 1.0131x over previous
//
#include <hip/hip_runtime.h>
#include <cstdint>
#include <cstddef>

typedef unsigned int UINT;
typedef unsigned short USHORT;

// ---------- constants ----------
// B=32 S=128 V=32000 NT=64 NE=100 H=400 NL=128 NM=100
#define TOKENS 4096      // B*S
#define HID 400
#define G4 1600          // 4*H
#define SEQ 128
#define NB 32
#define NPOS 127         // S-1
#define NROW 4064        // B*NPOS
#define LD1T 4064
#define CHUNK_B 4        // batches per biaffine/transpose chunk

// lstm j-split config
#define NSLICE 4
#define JS 100           // hidden outputs per slice-block
#define KS 10            // k-slices (threads per j)
#define KP 20            // k-pairs per thread (KS*KP = 200 pairs = 400 k)

typedef _Float16 h2f __attribute__((ext_vector_type(2)));

__device__ __forceinline__ float dot2f(UINT w, UINT h, float acc){
#if __has_builtin(__builtin_amdgcn_fdot2)
    return __builtin_amdgcn_fdot2(__builtin_bit_cast(h2f, w), __builtin_bit_cast(h2f, h), acc, false);
#else
    h2f a = __builtin_bit_cast(h2f, w); h2f b = __builtin_bit_cast(h2f, h);
    return acc + (float)a.x * (float)b.x + (float)a.y * (float)b.y;
#endif
}

__device__ __forceinline__ float sigm(float x){ return 1.f / (1.f + __expf(-x)); }
__device__ __forceinline__ float tanh_f(float x){ float e = __expf(2.f * x); return (e - 1.f) / (e + 1.f); }

// ---------- 1) Whh (3,2,1600,400) f32 -> f16 k-pair-packed, gate-interleaved ----------
// uint4 per (ld, k2, j): { wi, wf, wg, wo }, each UINT = f16 pair (k=2*k2, 2*k2+1)
__global__ __launch_bounds__(256) void k_convert_whh(const float* __restrict__ whh, UINT* __restrict__ wpk){
    int idx = blockIdx.x * 256 + threadIdx.x;      // 0 .. 479,999
    if (idx >= 480000) return;
    int ld_i = idx / 80000;
    int rem  = idx % 80000;
    int k2 = rem / 400;
    int j  = rem % 400;
    const float* srcb = whh + (size_t)ld_i * G4 * HID + 2 * k2;
    UINT p[4];
    #pragma unroll
    for (int g = 0; g < 4; g++){
        const float* src = srcb + (size_t)(g * HID + j) * HID;
        _Float16 w0 = (_Float16)src[0];
        _Float16 w1 = (_Float16)src[1];
        p[g] = (UINT)__builtin_bit_cast(USHORT, w0) | ((UINT)__builtin_bit_cast(USHORT, w1) << 16);
    }
    uint4 v; v.x = p[0]; v.y = p[1]; v.z = p[2]; v.w = p[3];
    ((uint4*)wpk)[(size_t)ld_i * 80000 + (size_t)k2 * 400 + j] = v;
}

// ---------- 2) embedding concat -> x (4096 x 200) fp32 ----------
__global__ __launch_bounds__(64) void k_embed(const int* __restrict__ words, const int* __restrict__ tags,
                                              const float* __restrict__ wemb, const float* __restrict__ temb,
                                              float* __restrict__ xA){
    int tok = blockIdx.x;
    int w = words[tok], tg = tags[tok];
    float* dst = xA + (size_t)tok * 200;
    for (int i = threadIdx.x; i < 100; i += 64){
        dst[i]       = wemb[(size_t)w * 100 + i];
        dst[100 + i] = temb[(size_t)tg * 100 + i];
    }
}

// ---------- 3) input projection GEMM ----------
__global__ __launch_bounds__(256) void k_gemm_ih(const float* __restrict__ X, int ldX, int K,
                                                 const float* __restrict__ Wih, const float* __restrict__ bias,
                                                 _Float16* __restrict__ Zh){
    int dir = blockIdx.z;
    int o0 = blockIdx.x * 64, tok0 = blockIdx.y * 64;
    const float* W  = Wih + (size_t)dir * G4 * K;
    const float* bb = bias + dir * G4;
    _Float16* Zd = Zh + (size_t)dir * TOKENS * G4;
    __shared__ float Xs[16][68];
    __shared__ float Ws[16][68];
    int tid = threadIdx.x;
    int tx = tid & 15, ty = tid >> 4;
    float acc[4][4];
    #pragma unroll
    for (int j = 0; j < 4; j++){
        float bv = bb[o0 + tx * 4 + j];
        #pragma unroll
        for (int i = 0; i < 4; i++) acc[i][j] = bv;
    }
    int lr = tid >> 2;
    int lc = (tid & 3) * 4;
    for (int k0 = 0; k0 < K; k0 += 16){
        float4 xv = {0.f,0.f,0.f,0.f};
        float4 wv = {0.f,0.f,0.f,0.f};
        if (k0 + lc < K){
            xv = *(const float4*)(X + (size_t)(tok0 + lr) * ldX + k0 + lc);
            wv = *(const float4*)(W + (size_t)(o0 + lr) * K + k0 + lc);
        }
        __syncthreads();
        Xs[lc+0][lr] = xv.x; Xs[lc+1][lr] = xv.y; Xs[lc+2][lr] = xv.z; Xs[lc+3][lr] = xv.w;
        Ws[lc+0][lr] = wv.x; Ws[lc+1][lr] = wv.y; Ws[lc+2][lr] = wv.z; Ws[lc+3][lr] = wv.w;
        __syncthreads();
        #pragma unroll
        for (int kk = 0; kk < 16; kk++){
            float4 a = *(const float4*)&Xs[kk][ty * 4];
            float4 w = *(const float4*)&Ws[kk][tx * 4];
            float av[4] = {a.x, a.y, a.z, a.w};
            float wv2[4] = {w.x, w.y, w.z, w.w};
            #pragma unroll
            for (int i = 0; i < 4; i++)
                #pragma unroll
                for (int j = 0; j < 4; j++)
                    acc[i][j] += av[i] * wv2[j];
        }
    }
    #pragma unroll
    for (int i = 0; i < 4; i++){
        _Float16* zr = Zd + (size_t)(tok0 + ty * 4 + i) * G4 + o0 + tx * 4;
        #pragma unroll
        for (int j = 0; j < 4; j++) zr[j] = (_Float16)acc[i][j];
    }
}

// ---------- 4) LSTM: 4 blocks per chain, weights resident in VGPRs ----------
// grid: 256 blocks, block index = slice*64 + chain (chain = bi*2+dir). 1024 threads.
// thread (ksl = tid/100, j = tid%100) holds 20 uint4 weights (k2 = ksl*20..+20, output gj = slice*100+j).
// Per timestep: dot partials -> LDS reduce (tid<100 own cell state) -> h-slice exchange via
// device-scope atomics (release/acquire flags, parity double-buffered slots).
__global__ __launch_bounds__(1024) void k_lstm2(const _Float16* __restrict__ Zh, const UINT* __restrict__ wpk,
                                                float* __restrict__ Xout, int layer,
                                                UINT* __restrict__ Hbuf, UINT* __restrict__ flags){
    int bidx = blockIdx.x;
    int chain = bidx & 63;          // bi*2 + dir
    int slice = bidx >> 6;          // 0..3
    int bi = chain >> 1, dir = chain & 1;
    int tid = threadIdx.x;
    int ksl = tid / 100;            // 0..9 for active
    int j   = tid - ksl * 100;      // 0..99
    bool act = (tid < 1000);
    int gj = slice * JS + j;

    const uint4* wp4 = (const uint4*)wpk + (size_t)(layer * 2 + dir) * 80000;
    const _Float16* Zd = Zh + (size_t)dir * TOKENS * G4 + (size_t)bi * SEQ * G4;
    float* Xo = Xout + (size_t)bi * SEQ * 800 + dir * HID;

    // resident weights: 20 uint4 = 80 VGPRs
    uint4 w[KP];
    if (act){
        #pragma unroll
        for (int kk = 0; kk < KP; kk++)
            w[kk] = wp4[(size_t)(ksl * KP + kk) * 400 + gj];
    }

    __shared__ __align__(16) UINT hu32[200];        // full h as f16 pairs
    __shared__ float psum[4][KS][JS];               // 16 KB partials
    __shared__ _Float16 hnew[JS];

    for (int i = tid; i < 200; i += 1024) hu32[i] = 0u;
    __syncthreads();

    UINT* myflag   = flags + chain * 4 + slice;
    UINT* slotbase = Hbuf + (size_t)chain * 2 * 200;
    const UINT eb = (UINT)(layer * SEQ);
    float c = 0.f;

    for (int s = 0; s < SEQ; s++){
        int t = dir ? (SEQ - 1 - s) : s;
        // 1) dot partials (weights from VGPRs, h broadcast from LDS)
        if (act){
            float a0 = 0.f, a1 = 0.f, a2 = 0.f, a3 = 0.f;
            const UINT* hb32 = hu32 + ksl * KP;
            #pragma unroll
            for (int kk = 0; kk < KP; kk += 4){
                uint4 hh = *(const uint4*)(hb32 + kk);
                UINT hv[4] = {hh.x, hh.y, hh.z, hh.w};
                #pragma unroll
                for (int q = 0; q < 4; q++){
                    uint4 ww = w[kk + q];
                    a0 = dot2f(ww.x, hv[q], a0);
                    a1 = dot2f(ww.y, hv[q], a1);
                    a2 = dot2f(ww.z, hv[q], a2);
                    a3 = dot2f(ww.w, hv[q], a3);
                }
            }
            psum[0][ksl][j] = a0; psum[1][ksl][j] = a1;
            psum[2][ksl][j] = a2; psum[3][ksl][j] = a3;
        }
        __syncthreads();
        // 2) reduce + cell update (tid<100 <=> ksl==0, j=tid)
        if (tid < JS){
            const _Float16* zr = Zd + (size_t)t * G4;
            float ai = (float)zr[gj], af = (float)zr[HID + gj];
            float ag = (float)zr[2*HID + gj], ao = (float)zr[3*HID + gj];
            #pragma unroll
            for (int k = 0; k < KS; k++){
                ai += psum[0][k][tid]; af += psum[1][k][tid];
                ag += psum[2][k][tid]; ao += psum[3][k][tid];
            }
            float ig = sigm(ai), fg = sigm(af), gg = tanh_f(ag), og = sigm(ao);
            c = fg * c + ig * gg;
            float hval = og * tanh_f(c);
            Xo[(size_t)t * 800 + gj] = hval;
            hnew[tid] = (_Float16)hval;
        }
        __syncthreads();
        // 3) publish own slice (data stores then flag, same wave => ordered), peers poll
        UINT epoch = eb + (UINT)s + 1u;
        UINT* slot = slotbase + (s & 1) * 200;
        if (tid < 50){
            UINT pk = (UINT)__builtin_bit_cast(USHORT, hnew[2*tid])
                    | ((UINT)__builtin_bit_cast(USHORT, hnew[2*tid+1]) << 16);
            hu32[slice * 50 + tid] = pk;                     // own slice locally
            __hip_atomic_store(slot + slice * 50 + tid, pk, __ATOMIC_RELAXED, __HIP_MEMORY_SCOPE_AGENT);
            if (tid == 0)
                __hip_atomic_store(myflag, epoch, __ATOMIC_RELEASE, __HIP_MEMORY_SCOPE_AGENT);
        } else if (tid >= 64 && tid < 67){
            int p = tid - 64;
            int ps = p + (p >= slice);
            while (__hip_atomic_load(flags + chain * 4 + ps, __ATOMIC_ACQUIRE, __HIP_MEMORY_SCOPE_AGENT) < epoch)
                __builtin_amdgcn_s_sleep(2);
        }
        __syncthreads();
        // 4) fetch peer slices into hu32
        if (tid < 150){
            int p = tid / 50, i = tid - p * 50;
            int ps = p + (p >= slice);
            UINT v = __hip_atomic_load(slot + ps * 50 + i, __ATOMIC_RELAXED, __HIP_MEMORY_SCOPE_AGENT);
            hu32[ps * 50 + i] = v;
        }
        __syncthreads();
    }
}

// ---------- 5) MLPs -> transposed l1T/r1T [feature][row] ----------
__global__ __launch_bounds__(256) void k_mlp(const float* __restrict__ X,
                                             const float* __restrict__ Wl, const float* __restrict__ bl,
                                             const float* __restrict__ Wr, const float* __restrict__ br,
                                             float* __restrict__ l1T, float* __restrict__ r1T){
    int r = blockIdx.x;            // 0..4063
    int b = r / NPOS, x = r % NPOS;
    __shared__ float feat[800];
    const float* xrow = X + (size_t)(b * SEQ + x) * 800;
    int tid = threadIdx.x;
    for (int k = tid; k < 800; k += 256) feat[k] = (k < 400) ? xrow[k] : xrow[800 + k];
    __syncthreads();
    if (tid < 200){
        int isl = (tid < 100);
        int m = isl ? tid : tid - 100;
        const float* W = (isl ? Wl : Wr) + (size_t)m * 800;
        float acc = (isl ? bl : br)[m];
        for (int k = 0; k < 800; k += 4){
            float4 w4 = *(const float4*)(W + k);
            acc += w4.x * feat[k]   + w4.y * feat[k+1]
                 + w4.z * feat[k+2] + w4.w * feat[k+3];
        }
        float v = acc > 0.f ? acc : 0.1f * acc;
        (isl ? l1T : r1T)[(size_t)m * LD1T + r] = v;
    } else if (tid == 200){ l1T[(size_t)100 * LD1T + r] = 1.0f; }
    else if (tid == 201){ r1T[(size_t)100 * LD1T + r] = 1.0f; }
}

// ---------- 6a) biaffine -> T[bb][o][x][ypad128], coalesced stores ----------
__global__ __launch_bounds__(256) void k_biaffineT(const float* __restrict__ l1T, const float* __restrict__ r1T,
                                                   const float* __restrict__ BW, float* __restrict__ T, int b0){
    int o = blockIdx.x, bb = blockIdx.y, b = b0 + bb;
    extern __shared__ float sm[];
    float* Wl = sm;                  // 101*104
    float* Rt = sm + 101 * 104;      // 101*128
    float* Vt = Rt + 101 * 128;      // 101*128
    float* Lt = sm;                  // reuse after stage A
    int tid = threadIdx.x;
    const float* wo = BW + (size_t)o * 10201;
    for (int idx = tid; idx < 10201; idx += 256){
        int i = idx / 101, jj = idx % 101;
        Wl[i * 104 + jj] = wo[idx];
    }
    const float* rb = r1T + b * NPOS;
    for (int idx = tid; idx < 101 * 128; idx += 256){
        int jj = idx >> 7, y = idx & 127;
        Rt[idx] = (y < NPOS) ? rb[(size_t)jj * LD1T + y] : 0.f;
    }
    __syncthreads();
    {   // stage A
        int ty = tid & 31, ti = tid >> 5;
        for (int i = ti; i < 101; i += 8){
            float a0 = 0.f, a1 = 0.f, a2 = 0.f, a3 = 0.f;
            const float* wrow = Wl + i * 104;
            #pragma unroll 2
            for (int jj = 0; jj < 101; jj++){
                float w = wrow[jj];
                float4 r4 = *(const float4*)(Rt + jj * 128 + ty * 4);
                a0 += w * r4.x; a1 += w * r4.y; a2 += w * r4.z; a3 += w * r4.w;
            }
            float4 v; v.x = a0; v.y = a1; v.z = a2; v.w = a3;
            *(float4*)(Vt + i * 128 + ty * 4) = v;
        }
    }
    __syncthreads();
    const float* lb = l1T + b * NPOS;
    for (int idx = tid; idx < 101 * 128; idx += 256){
        int ii = idx >> 7, x = idx & 127;
        Lt[idx] = (x < NPOS) ? lb[(size_t)ii * LD1T + x] : 0.f;
    }
    __syncthreads();
    {   // stage B: lanes vary y -> coalesced T stores
        int ty = tid & 31;
        int tx8 = tid >> 5;
        float* tb = T + (size_t)(bb * 128 + o) * 127 * 128;
        for (int xp = 0; xp < 4; xp++){
            int x0 = (tx8 + 8 * xp) * 4;
            float accm[4][4] = {};
            for (int i = 0; i < 101; i++){
                float4 l4 = *(const float4*)(Lt + i * 128 + x0);
                float4 v4 = *(const float4*)(Vt + i * 128 + ty * 4);
                float lv[4] = {l4.x, l4.y, l4.z, l4.w};
                float vv[4] = {v4.x, v4.y, v4.z, v4.w};
                #pragma unroll
                for (int xx = 0; xx < 4; xx++)
                    #pragma unroll
                    for (int yy = 0; yy < 4; yy++)
                        accm[xx][yy] += lv[xx] * vv[yy];
            }
            #pragma unroll
            for (int xx = 0; xx < 4; xx++){
                int x = x0 + xx;
                if (x >= NPOS) continue;
                float4 wv; wv.x = accm[xx][0]; wv.y = accm[xx][1]; wv.z = accm[xx][2]; wv.w = accm[xx][3];
                *(float4*)(tb + (size_t)x * 128 + ty * 4) = wv;
            }
        }
    }
}

// ---------- 6b) transpose T[bb][o][x][ypad] -> out[b][x][y][o] ----------
__global__ __launch_bounds__(256) void k_transpose(const float* __restrict__ T, float* __restrict__ out, int b0){
    int x = blockIdx.x, bb = blockIdx.y, b = b0 + bb;
    extern __shared__ float ts[];    // [o][129]
    int tid = threadIdx.x;
    for (int idx = tid; idx < 128 * 32; idx += 256){
        int o = idx >> 5, y4 = idx & 31;
        float4 v = *(const float4*)(T + ((size_t)(bb * 128 + o) * 127 + x) * 128 + y4 * 4);
        float* d = ts + o * 129 + y4 * 4;
        d[0] = v.x; d[1] = v.y; d[2] = v.z; d[3] = v.w;
    }
    __syncthreads();
    float* ob = out + ((size_t)(b * NPOS + x)) * NPOS * 128;
    for (int idx = tid; idx < NPOS * 32; idx += 256){
        int y = idx >> 5, o4 = idx & 31;
        float4 w;
        w.x = ts[(o4 * 4 + 0) * 129 + y];
        w.y = ts[(o4 * 4 + 1) * 129 + y];
        w.z = ts[(o4 * 4 + 2) * 129 + y];
        w.w = ts[(o4 * 4 + 3) * 129 + y];
        *(float4*)(ob + (size_t)y * 128 + o4 * 4) = w;
    }
}

extern "C" void kernel_launch(void* const* d_in, const int* in_sizes, int n_in,
                              void* d_out, int out_size, void* d_ws, size_t ws_size,
                              hipStream_t stream) {
    const int* words = (const int*)d_in[0];
    const int* tags  = (const int*)d_in[1];
    const float* wemb = (const float*)d_in[2];
    const float* temb = (const float*)d_in[3];
    const float* wih[3] = {(const float*)d_in[4], (const float*)d_in[5], (const float*)d_in[6]};
    const float* whh  = (const float*)d_in[7];
    const float* bias = (const float*)d_in[8];
    const float* mlW = (const float*)d_in[9];
    const float* mlb = (const float*)d_in[10];
    const float* mrW = (const float*)d_in[11];
    const float* mrb = (const float*)d_in[12];
    const float* bw  = (const float*)d_in[13];
    float* out = (float*)d_out;

    // workspace layout (bytes):
    //   [0 .. 13,107,200)            x f32 (reused as T after k_mlp)
    //   [13,107,200 .. 39,321,600)   Zh f16
    //   [39,321,600 .. 47,001,600)   wpk u32 (l1T/r1T overlay after last LSTM)
    //   [47,001,600 .. +103,424)     Hbuf (102,400 B) + flags (1,024 B)  [fallback: tail of out]
    char* base = (char*)d_ws;
    float*     x   = (float*)base;
    _Float16*  Zh  = (_Float16*)(base + 13107200);
    UINT*      wpk = (UINT*)(base + 13107200 + 26214400);
    float*     l1T = (float*)(base + 39321600);
    float*     r1T = l1T + (size_t)104 * LD1T;
    float*     T   = (float*)base;

    const size_t SYNC_BYTES = 102400 + 1024;
    char* sync_base;
    if (ws_size >= (size_t)47001600 + SYNC_BYTES){
        sync_base = base + 47001600;
    } else {
        // tail of out: scratch during LSTM, fully overwritten later by k_transpose
        size_t off = ((size_t)out_size - SYNC_BYTES) & ~(size_t)255;
        sync_base = (char*)d_out + off;
    }
    UINT* Hbuf  = (UINT*)sync_base;           // 64 chains * 2 parity * 200 u32
    UINT* flags = Hbuf + 51200;               // 256 u32

    (void)hipMemsetAsync(flags, 0, 1024, stream);
    k_convert_whh<<<1875, 256, 0, stream>>>(whh, wpk);
    k_embed<<<TOKENS, 64, 0, stream>>>(words, tags, wemb, temb, x);

    for (int l = 0; l < 3; l++){
        int K = l ? 800 : 200;
        k_gemm_ih<<<dim3(25, 64, 2), 256, 0, stream>>>(x, K, K, wih[l], bias + l * 2 * G4, Zh);
        k_lstm2<<<256, 1024, 0, stream>>>(Zh, wpk, x, l, Hbuf, flags);
    }
    k_mlp<<<NROW, 256, 0, stream>>>(x, mlW, mlb, mrW, mrb, l1T, r1T);

    (void)hipFuncSetAttribute((const void*)k_biaffineT, hipFuncAttributeMaxDynamicSharedMemorySize, 145440);
    (void)hipFuncSetAttribute((const void*)k_transpose, hipFuncAttributeMaxDynamicSharedMemorySize, 66048);
    for (int c = 0; c < NB / CHUNK_B; c++){
        k_biaffineT<<<dim3(128, CHUNK_B), 256, 145440, stream>>>(l1T, r1T, bw, T, c * CHUNK_B);
        k_transpose<<<dim3(NPOS, CHUNK_B), 256, 66048, stream>>>(T, out, c * CHUNK_B);
    }
}

// Round 6
// 6716.701 us; speedup vs baseline: 1.0508x; 1.0372x over previous
//
#include <hip/hip_runtime.h>
#include <cstdint>
#include <cstddef>

typedef unsigned int UINT;
typedef unsigned short USHORT;

// ---------- constants ----------
// B=32 S=128 V=32000 NT=64 NE=100 H=400 NL=128 NM=100
#define TOKENS 4096      // B*S
#define HID 400
#define G4 1600          // 4*H
#define SEQ 128
#define NB 32
#define NPOS 127         // S-1
#define NROW 4064        // B*NPOS
#define LD1T 4064
#define CHUNK_B 4        // batches per biaffine/transpose chunk

// lstm j-split config: 4 slice-blocks per chain, 512 threads each
#define NSLICE 4
#define JS 100           // hidden outputs per slice-block
#define KS 5             // k-slices (threads per j)
#define KP 40            // k-pairs per thread (KS*KP = 200 pairs = 400 k)

typedef _Float16 h2f __attribute__((ext_vector_type(2)));

__device__ __forceinline__ float dot2f(UINT w, UINT h, float acc){
#if __has_builtin(__builtin_amdgcn_fdot2)
    return __builtin_amdgcn_fdot2(__builtin_bit_cast(h2f, w), __builtin_bit_cast(h2f, h), acc, false);
#else
    h2f a = __builtin_bit_cast(h2f, w); h2f b = __builtin_bit_cast(h2f, h);
    return acc + (float)a.x * (float)b.x + (float)a.y * (float)b.y;
#endif
}

__device__ __forceinline__ float sigm(float x){ return 1.f / (1.f + __expf(-x)); }
__device__ __forceinline__ float tanh_f(float x){ float e = __expf(2.f * x); return (e - 1.f) / (e + 1.f); }

// ---------- 1) Whh (3,2,1600,400) f32 -> f16 k-pair-packed, gate-interleaved ----------
// uint4 per (ld, k2, j): { wi, wf, wg, wo }, each UINT = f16 pair (k=2*k2, 2*k2+1)
__global__ __launch_bounds__(256) void k_convert_whh(const float* __restrict__ whh, UINT* __restrict__ wpk){
    int idx = blockIdx.x * 256 + threadIdx.x;      // 0 .. 479,999
    if (idx >= 480000) return;
    int ld_i = idx / 80000;
    int rem  = idx % 80000;
    int k2 = rem / 400;
    int j  = rem % 400;
    const float* srcb = whh + (size_t)ld_i * G4 * HID + 2 * k2;
    UINT p[4];
    #pragma unroll
    for (int g = 0; g < 4; g++){
        const float* src = srcb + (size_t)(g * HID + j) * HID;
        _Float16 w0 = (_Float16)src[0];
        _Float16 w1 = (_Float16)src[1];
        p[g] = (UINT)__builtin_bit_cast(USHORT, w0) | ((UINT)__builtin_bit_cast(USHORT, w1) << 16);
    }
    uint4 v; v.x = p[0]; v.y = p[1]; v.z = p[2]; v.w = p[3];
    ((uint4*)wpk)[(size_t)ld_i * 80000 + (size_t)k2 * 400 + j] = v;
}

// ---------- 2) embedding concat -> x (4096 x 200) fp32 ----------
__global__ __launch_bounds__(64) void k_embed(const int* __restrict__ words, const int* __restrict__ tags,
                                              const float* __restrict__ wemb, const float* __restrict__ temb,
                                              float* __restrict__ xA){
    int tok = blockIdx.x;
    int w = words[tok], tg = tags[tok];
    float* dst = xA + (size_t)tok * 200;
    for (int i = threadIdx.x; i < 100; i += 64){
        dst[i]       = wemb[(size_t)w * 100 + i];
        dst[100 + i] = temb[(size_t)tg * 100 + i];
    }
}

// ---------- 3) input projection GEMM ----------
__global__ __launch_bounds__(256) void k_gemm_ih(const float* __restrict__ X, int ldX, int K,
                                                 const float* __restrict__ Wih, const float* __restrict__ bias,
                                                 _Float16* __restrict__ Zh){
    int dir = blockIdx.z;
    int o0 = blockIdx.x * 64, tok0 = blockIdx.y * 64;
    const float* W  = Wih + (size_t)dir * G4 * K;
    const float* bb = bias + dir * G4;
    _Float16* Zd = Zh + (size_t)dir * TOKENS * G4;
    __shared__ float Xs[16][68];
    __shared__ float Ws[16][68];
    int tid = threadIdx.x;
    int tx = tid & 15, ty = tid >> 4;
    float acc[4][4];
    #pragma unroll
    for (int j = 0; j < 4; j++){
        float bv = bb[o0 + tx * 4 + j];
        #pragma unroll
        for (int i = 0; i < 4; i++) acc[i][j] = bv;
    }
    int lr = tid >> 2;
    int lc = (tid & 3) * 4;
    for (int k0 = 0; k0 < K; k0 += 16){
        float4 xv = {0.f,0.f,0.f,0.f};
        float4 wv = {0.f,0.f,0.f,0.f};
        if (k0 + lc < K){
            xv = *(const float4*)(X + (size_t)(tok0 + lr) * ldX + k0 + lc);
            wv = *(const float4*)(W + (size_t)(o0 + lr) * K + k0 + lc);
        }
        __syncthreads();
        Xs[lc+0][lr] = xv.x; Xs[lc+1][lr] = xv.y; Xs[lc+2][lr] = xv.z; Xs[lc+3][lr] = xv.w;
        Ws[lc+0][lr] = wv.x; Ws[lc+1][lr] = wv.y; Ws[lc+2][lr] = wv.z; Ws[lc+3][lr] = wv.w;
        __syncthreads();
        #pragma unroll
        for (int kk = 0; kk < 16; kk++){
            float4 a = *(const float4*)&Xs[kk][ty * 4];
            float4 w = *(const float4*)&Ws[kk][tx * 4];
            float av[4] = {a.x, a.y, a.z, a.w};
            float wv2[4] = {w.x, w.y, w.z, w.w};
            #pragma unroll
            for (int i = 0; i < 4; i++)
                #pragma unroll
                for (int j = 0; j < 4; j++)
                    acc[i][j] += av[i] * wv2[j];
        }
    }
    #pragma unroll
    for (int i = 0; i < 4; i++){
        _Float16* zr = Zd + (size_t)(tok0 + ty * 4 + i) * G4 + o0 + tx * 4;
        #pragma unroll
        for (int j = 0; j < 4; j++) zr[j] = (_Float16)acc[i][j];
    }
}

// ---------- 4) LSTM: 4 blocks per chain, weights resident in VGPRs ----------
// grid: 256 blocks = slice*64 + chain. 512 threads, __launch_bounds__(512,2) -> 256 VGPR budget.
// thread (ksl = tid/100 in 0..4, j = tid%100) holds 40 uint4 = 160 VGPRs of weights
// (k2 = ksl*40..+40, output gj = slice*100+j). Per timestep: dot partials -> LDS reduce
// (tid<100 own cell state) -> h-slice exchange via device-scope atomics (release/acquire
// flags, parity double-buffered slots).
__global__ __launch_bounds__(512, 2) void k_lstm2(const _Float16* __restrict__ Zh, const UINT* __restrict__ wpk,
                                                  float* __restrict__ Xout, int layer,
                                                  UINT* __restrict__ Hbuf, UINT* __restrict__ flags){
    int bidx = blockIdx.x;
    int chain = bidx & 63;          // bi*2 + dir
    int slice = bidx >> 6;          // 0..3
    int bi = chain >> 1, dir = chain & 1;
    int tid = threadIdx.x;
    int ksl = tid / 100;            // 0..5 (5 = inactive tail)
    int j   = tid - ksl * 100;      // 0..99
    bool act = (tid < 500);
    int gj = slice * JS + j;

    const uint4* wp4 = (const uint4*)wpk + (size_t)(layer * 2 + dir) * 80000;
    const _Float16* Zd = Zh + (size_t)dir * TOKENS * G4 + (size_t)bi * SEQ * G4;
    float* Xo = Xout + (size_t)bi * SEQ * 800 + dir * HID;

    // resident weights: 40 uint4 = 160 VGPRs. Unconditional load (clamped for tail threads)
    // so the array is uniformly defined -> register promotion.
    int kb  = act ? ksl * KP : 0;
    int gjc = act ? gj : slice * JS;
    uint4 w[KP];
    #pragma unroll
    for (int kk = 0; kk < KP; kk++)
        w[kk] = wp4[(size_t)(kb + kk) * 400 + gjc];

    __shared__ __align__(16) UINT hu32[200];        // full h as f16 pairs
    __shared__ float psum[4][KS][JS];               // 8 KB partials
    __shared__ _Float16 hnew[JS];

    for (int i = tid; i < 200; i += 512) hu32[i] = 0u;
    __syncthreads();

    UINT* myflag   = flags + chain * 4 + slice;
    UINT* slotbase = Hbuf + (size_t)chain * 2 * 200;
    const UINT eb = (UINT)(layer * SEQ);
    float c = 0.f;

    for (int s = 0; s < SEQ; s++){
        int t = dir ? (SEQ - 1 - s) : s;
        const _Float16* zr = Zd + (size_t)t * G4;
        float zi = 0.f, zf = 0.f, zg = 0.f, zo = 0.f;
        if (tid < JS){   // issue gate-bias loads early; latency hides under the dot loop
            zi = (float)zr[gj];         zf = (float)zr[HID + gj];
            zg = (float)zr[2*HID + gj]; zo = (float)zr[3*HID + gj];
        }
        // 1) dot partials (weights from VGPRs, h broadcast from LDS)
        if (act){
            float a0 = 0.f, a1 = 0.f, a2 = 0.f, a3 = 0.f;
            const UINT* hb = hu32 + kb;
            #pragma unroll
            for (int kk = 0; kk < KP; kk += 4){
                uint4 hh = *(const uint4*)(hb + kk);
                UINT hv[4] = {hh.x, hh.y, hh.z, hh.w};
                #pragma unroll
                for (int q = 0; q < 4; q++){
                    uint4 ww = w[kk + q];
                    a0 = dot2f(ww.x, hv[q], a0);
                    a1 = dot2f(ww.y, hv[q], a1);
                    a2 = dot2f(ww.z, hv[q], a2);
                    a3 = dot2f(ww.w, hv[q], a3);
                }
            }
            psum[0][ksl][j] = a0; psum[1][ksl][j] = a1;
            psum[2][ksl][j] = a2; psum[3][ksl][j] = a3;
        }
        __syncthreads();
        // 2) reduce + cell update (tid<100 <=> ksl==0, j=tid)
        if (tid < JS){
            float ai = zi, af = zf, ag = zg, ao = zo;
            #pragma unroll
            for (int k = 0; k < KS; k++){
                ai += psum[0][k][tid]; af += psum[1][k][tid];
                ag += psum[2][k][tid]; ao += psum[3][k][tid];
            }
            float ig = sigm(ai), fg = sigm(af), gg = tanh_f(ag), og = sigm(ao);
            c = fg * c + ig * gg;
            float hval = og * tanh_f(c);
            Xo[(size_t)t * 800 + gj] = hval;
            hnew[tid] = (_Float16)hval;
        }
        __syncthreads();
        // 3) publish own slice (data stores then flag release), 3 threads poll peers
        UINT epoch = eb + (UINT)s + 1u;
        UINT* slot = slotbase + (s & 1) * 200;
        if (tid < 50){
            UINT pk = (UINT)__builtin_bit_cast(USHORT, hnew[2*tid])
                    | ((UINT)__builtin_bit_cast(USHORT, hnew[2*tid+1]) << 16);
            hu32[slice * 50 + tid] = pk;                     // own slice locally
            __hip_atomic_store(slot + slice * 50 + tid, pk, __ATOMIC_RELAXED, __HIP_MEMORY_SCOPE_AGENT);
            if (tid == 0)
                __hip_atomic_store(myflag, epoch, __ATOMIC_RELEASE, __HIP_MEMORY_SCOPE_AGENT);
        } else if (tid >= 64 && tid < 67){
            int p = tid - 64;
            int ps = p + (p >= slice);
            while (__hip_atomic_load(flags + chain * 4 + ps, __ATOMIC_ACQUIRE, __HIP_MEMORY_SCOPE_AGENT) < epoch)
                __builtin_amdgcn_s_sleep(2);
        }
        __syncthreads();
        // 4) fetch peer slices into hu32
        if (tid < 150){
            int p = tid / 50, i = tid - p * 50;
            int ps = p + (p >= slice);
            UINT v = __hip_atomic_load(slot + ps * 50 + i, __ATOMIC_RELAXED, __HIP_MEMORY_SCOPE_AGENT);
            hu32[ps * 50 + i] = v;
        }
        __syncthreads();
    }
}

// ---------- 5) MLPs -> transposed l1T/r1T [feature][row] ----------
__global__ __launch_bounds__(256) void k_mlp(const float* __restrict__ X,
                                             const float* __restrict__ Wl, const float* __restrict__ bl,
                                             const float* __restrict__ Wr, const float* __restrict__ br,
                                             float* __restrict__ l1T, float* __restrict__ r1T){
    int r = blockIdx.x;            // 0..4063
    int b = r / NPOS, x = r % NPOS;
    __shared__ float feat[800];
    const float* xrow = X + (size_t)(b * SEQ + x) * 800;
    int tid = threadIdx.x;
    for (int k = tid; k < 800; k += 256) feat[k] = (k < 400) ? xrow[k] : xrow[800 + k];
    __syncthreads();
    if (tid < 200){
        int isl = (tid < 100);
        int m = isl ? tid : tid - 100;
        const float* W = (isl ? Wl : Wr) + (size_t)m * 800;
        float acc = (isl ? bl : br)[m];
        for (int k = 0; k < 800; k += 4){
            float4 w4 = *(const float4*)(W + k);
            acc += w4.x * feat[k]   + w4.y * feat[k+1]
                 + w4.z * feat[k+2] + w4.w * feat[k+3];
        }
        float v = acc > 0.f ? acc : 0.1f * acc;
        (isl ? l1T : r1T)[(size_t)m * LD1T + r] = v;
    } else if (tid == 200){ l1T[(size_t)100 * LD1T + r] = 1.0f; }
    else if (tid == 201){ r1T[(size_t)100 * LD1T + r] = 1.0f; }
}

// ---------- 6a) biaffine -> T[bb][o][x][ypad128], coalesced stores ----------
__global__ __launch_bounds__(256) void k_biaffineT(const float* __restrict__ l1T, const float* __restrict__ r1T,
                                                   const float* __restrict__ BW, float* __restrict__ T, int b0){
    int o = blockIdx.x, bb = blockIdx.y, b = b0 + bb;
    extern __shared__ float sm[];
    float* Wl = sm;                  // 101*104
    float* Rt = sm + 101 * 104;      // 101*128
    float* Vt = Rt + 101 * 128;      // 101*128
    float* Lt = sm;                  // reuse after stage A
    int tid = threadIdx.x;
    const float* wo = BW + (size_t)o * 10201;
    for (int idx = tid; idx < 10201; idx += 256){
        int i = idx / 101, jj = idx % 101;
        Wl[i * 104 + jj] = wo[idx];
    }
    const float* rb = r1T + b * NPOS;
    for (int idx = tid; idx < 101 * 128; idx += 256){
        int jj = idx >> 7, y = idx & 127;
        Rt[idx] = (y < NPOS) ? rb[(size_t)jj * LD1T + y] : 0.f;
    }
    __syncthreads();
    {   // stage A
        int ty = tid & 31, ti = tid >> 5;
        for (int i = ti; i < 101; i += 8){
            float a0 = 0.f, a1 = 0.f, a2 = 0.f, a3 = 0.f;
            const float* wrow = Wl + i * 104;
            #pragma unroll 2
            for (int jj = 0; jj < 101; jj++){
                float w = wrow[jj];
                float4 r4 = *(const float4*)(Rt + jj * 128 + ty * 4);
                a0 += w * r4.x; a1 += w * r4.y; a2 += w * r4.z; a3 += w * r4.w;
            }
            float4 v; v.x = a0; v.y = a1; v.z = a2; v.w = a3;
            *(float4*)(Vt + i * 128 + ty * 4) = v;
        }
    }
    __syncthreads();
    const float* lb = l1T + b * NPOS;
    for (int idx = tid; idx < 101 * 128; idx += 256){
        int ii = idx >> 7, x = idx & 127;
        Lt[idx] = (x < NPOS) ? lb[(size_t)ii * LD1T + x] : 0.f;
    }
    __syncthreads();
    {   // stage B: lanes vary y -> coalesced T stores
        int ty = tid & 31;
        int tx8 = tid >> 5;
        float* tb = T + (size_t)(bb * 128 + o) * 127 * 128;
        for (int xp = 0; xp < 4; xp++){
            int x0 = (tx8 + 8 * xp) * 4;
            float accm[4][4] = {};
            for (int i = 0; i < 101; i++){
                float4 l4 = *(const float4*)(Lt + i * 128 + x0);
                float4 v4 = *(const float4*)(Vt + i * 128 + ty * 4);
                float lv[4] = {l4.x, l4.y, l4.z, l4.w};
                float vv[4] = {v4.x, v4.y, v4.z, v4.w};
                #pragma unroll
                for (int xx = 0; xx < 4; xx++)
                    #pragma unroll
                    for (int yy = 0; yy < 4; yy++)
                        accm[xx][yy] += lv[xx] * vv[yy];
            }
            #pragma unroll
            for (int xx = 0; xx < 4; xx++){
                int x = x0 + xx;
                if (x >= NPOS) continue;
                float4 wv; wv.x = accm[xx][0]; wv.y = accm[xx][1]; wv.z = accm[xx][2]; wv.w = accm[xx][3];
                *(float4*)(tb + (size_t)x * 128 + ty * 4) = wv;
            }
        }
    }
}

// ---------- 6b) transpose T[bb][o][x][ypad] -> out[b][x][y][o] ----------
__global__ __launch_bounds__(256) void k_transpose(const float* __restrict__ T, float* __restrict__ out, int b0){
    int x = blockIdx.x, bb = blockIdx.y, b = b0 + bb;
    extern __shared__ float ts[];    // [o][129]
    int tid = threadIdx.x;
    for (int idx = tid; idx < 128 * 32; idx += 256){
        int o = idx >> 5, y4 = idx & 31;
        float4 v = *(const float4*)(T + ((size_t)(bb * 128 + o) * 127 + x) * 128 + y4 * 4);
        float* d = ts + o * 129 + y4 * 4;
        d[0] = v.x; d[1] = v.y; d[2] = v.z; d[3] = v.w;
    }
    __syncthreads();
    float* ob = out + ((size_t)(b * NPOS + x)) * NPOS * 128;
    for (int idx = tid; idx < NPOS * 32; idx += 256){
        int y = idx >> 5, o4 = idx & 31;
        float4 w;
        w.x = ts[(o4 * 4 + 0) * 129 + y];
        w.y = ts[(o4 * 4 + 1) * 129 + y];
        w.z = ts[(o4 * 4 + 2) * 129 + y];
        w.w = ts[(o4 * 4 + 3) * 129 + y];
        *(float4*)(ob + (size_t)y * 128 + o4 * 4) = w;
    }
}

extern "C" void kernel_launch(void* const* d_in, const int* in_sizes, int n_in,
                              void* d_out, int out_size, void* d_ws, size_t ws_size,
                              hipStream_t stream) {
    const int* words = (const int*)d_in[0];
    const int* tags  = (const int*)d_in[1];
    const float* wemb = (const float*)d_in[2];
    const float* temb = (const float*)d_in[3];
    const float* wih[3] = {(const float*)d_in[4], (const float*)d_in[5], (const float*)d_in[6]};
    const float* whh  = (const float*)d_in[7];
    const float* bias = (const float*)d_in[8];
    const float* mlW = (const float*)d_in[9];
    const float* mlb = (const float*)d_in[10];
    const float* mrW = (const float*)d_in[11];
    const float* mrb = (const float*)d_in[12];
    const float* bw  = (const float*)d_in[13];
    float* out = (float*)d_out;

    // workspace layout (bytes):
    //   [0 .. 13,107,200)            x f32 (reused as T after k_mlp)
    //   [13,107,200 .. 39,321,600)   Zh f16
    //   [39,321,600 .. 47,001,600)   wpk u32 (l1T/r1T overlay after last LSTM)
    //   [47,001,600 .. +103,424)     Hbuf (102,400 B) + flags (1,024 B)  [fallback: tail of out]
    char* base = (char*)d_ws;
    float*     x   = (float*)base;
    _Float16*  Zh  = (_Float16*)(base + 13107200);
    UINT*      wpk = (UINT*)(base + 13107200 + 26214400);
    float*     l1T = (float*)(base + 39321600);
    float*     r1T = l1T + (size_t)104 * LD1T;
    float*     T   = (float*)base;

    const size_t SYNC_BYTES = 102400 + 1024;
    char* sync_base;
    if (ws_size >= (size_t)47001600 + SYNC_BYTES){
        sync_base = base + 47001600;
    } else {
        size_t off = ((size_t)out_size - SYNC_BYTES) & ~(size_t)255;
        sync_base = (char*)d_out + off;
    }
    UINT* Hbuf  = (UINT*)sync_base;           // 64 chains * 2 parity * 200 u32
    UINT* flags = Hbuf + 51200;               // 256 u32

    (void)hipMemsetAsync(flags, 0, 1024, stream);
    k_convert_whh<<<1875, 256, 0, stream>>>(whh, wpk);
    k_embed<<<TOKENS, 64, 0, stream>>>(words, tags, wemb, temb, x);

    for (int l = 0; l < 3; l++){
        int K = l ? 800 : 200;
        k_gemm_ih<<<dim3(25, 64, 2), 256, 0, stream>>>(x, K, K, wih[l], bias + l * 2 * G4, Zh);
        k_lstm2<<<256, 512, 0, stream>>>(Zh, wpk, x, l, Hbuf, flags);
    }
    k_mlp<<<NROW, 256, 0, stream>>>(x, mlW, mlb, mrW, mrb, l1T, r1T);

    (void)hipFuncSetAttribute((const void*)k_biaffineT, hipFuncAttributeMaxDynamicSharedMemorySize, 145440);
    (void)hipFuncSetAttribute((const void*)k_transpose, hipFuncAttributeMaxDynamicSharedMemorySize, 66048);
    for (int c = 0; c < NB / CHUNK_B; c++){
        k_biaffineT<<<dim3(128, CHUNK_B), 256, 145440, stream>>>(l1T, r1T, bw, T, c * CHUNK_B);
        k_transpose<<<dim3(NPOS, CHUNK_B), 256, 66048, stream>>>(T, out, c * CHUNK_B);
    }
}

// Round 7
// 4123.879 us; speedup vs baseline: 1.7115x; 1.6287x over previous
//
#include <hip/hip_runtime.h>
#include <cstdint>
#include <cstddef>

typedef unsigned int UINT;
typedef unsigned short USHORT;

// ---------- constants ----------
// B=32 S=128 V=32000 NT=64 NE=100 H=400 NL=128 NM=100
#define TOKENS 4096      // B*S
#define HID 400
#define G4 1600          // 4*H
#define SEQ 128
#define NB 32
#define NPOS 127         // S-1
#define NROW 4064        // B*NPOS
#define LD1T 4064
#define CHUNK_B 4        // batches per biaffine/transpose chunk

// lstm j-split config: 4 slice-blocks per chain, 512 threads each
#define NSLICE 4
#define JS 100           // hidden outputs per slice-block
#define KS 5             // k-slices (threads per j)
#define KP 40            // k-pairs per thread (KS*KP = 200 pairs = 400 k)

typedef _Float16 h2f __attribute__((ext_vector_type(2)));

__device__ __forceinline__ float dot2f(UINT w, UINT h, float acc){
#if __has_builtin(__builtin_amdgcn_fdot2)
    return __builtin_amdgcn_fdot2(__builtin_bit_cast(h2f, w), __builtin_bit_cast(h2f, h), acc, false);
#else
    h2f a = __builtin_bit_cast(h2f, w); h2f b = __builtin_bit_cast(h2f, h);
    return acc + (float)a.x * (float)b.x + (float)a.y * (float)b.y;
#endif
}

__device__ __forceinline__ float sigm(float x){ return 1.f / (1.f + __expf(-x)); }
__device__ __forceinline__ float tanh_f(float x){ float e = __expf(2.f * x); return (e - 1.f) / (e + 1.f); }

// ---------- 1) Whh (3,2,1600,400) f32 -> f16 k-pair-packed, gate-interleaved ----------
// uint4 per (ld, k2, j): { wi, wf, wg, wo }, each UINT = f16 pair (k=2*k2, 2*k2+1)
__global__ __launch_bounds__(256) void k_convert_whh(const float* __restrict__ whh, UINT* __restrict__ wpk){
    int idx = blockIdx.x * 256 + threadIdx.x;      // 0 .. 479,999
    if (idx >= 480000) return;
    int ld_i = idx / 80000;
    int rem  = idx % 80000;
    int k2 = rem / 400;
    int j  = rem % 400;
    const float* srcb = whh + (size_t)ld_i * G4 * HID + 2 * k2;
    UINT p[4];
    #pragma unroll
    for (int g = 0; g < 4; g++){
        const float* src = srcb + (size_t)(g * HID + j) * HID;
        _Float16 w0 = (_Float16)src[0];
        _Float16 w1 = (_Float16)src[1];
        p[g] = (UINT)__builtin_bit_cast(USHORT, w0) | ((UINT)__builtin_bit_cast(USHORT, w1) << 16);
    }
    uint4 v; v.x = p[0]; v.y = p[1]; v.z = p[2]; v.w = p[3];
    ((uint4*)wpk)[(size_t)ld_i * 80000 + (size_t)k2 * 400 + j] = v;
}

// ---------- 2) embedding concat -> x (4096 x 200) fp32 ----------
__global__ __launch_bounds__(64) void k_embed(const int* __restrict__ words, const int* __restrict__ tags,
                                              const float* __restrict__ wemb, const float* __restrict__ temb,
                                              float* __restrict__ xA){
    int tok = blockIdx.x;
    int w = words[tok], tg = tags[tok];
    float* dst = xA + (size_t)tok * 200;
    for (int i = threadIdx.x; i < 100; i += 64){
        dst[i]       = wemb[(size_t)w * 100 + i];
        dst[100 + i] = temb[(size_t)tg * 100 + i];
    }
}

// ---------- 3) input projection GEMM ----------
__global__ __launch_bounds__(256) void k_gemm_ih(const float* __restrict__ X, int ldX, int K,
                                                 const float* __restrict__ Wih, const float* __restrict__ bias,
                                                 _Float16* __restrict__ Zh){
    int dir = blockIdx.z;
    int o0 = blockIdx.x * 64, tok0 = blockIdx.y * 64;
    const float* W  = Wih + (size_t)dir * G4 * K;
    const float* bb = bias + dir * G4;
    _Float16* Zd = Zh + (size_t)dir * TOKENS * G4;
    __shared__ float Xs[16][68];
    __shared__ float Ws[16][68];
    int tid = threadIdx.x;
    int tx = tid & 15, ty = tid >> 4;
    float acc[4][4];
    #pragma unroll
    for (int j = 0; j < 4; j++){
        float bv = bb[o0 + tx * 4 + j];
        #pragma unroll
        for (int i = 0; i < 4; i++) acc[i][j] = bv;
    }
    int lr = tid >> 2;
    int lc = (tid & 3) * 4;
    for (int k0 = 0; k0 < K; k0 += 16){
        float4 xv = {0.f,0.f,0.f,0.f};
        float4 wv = {0.f,0.f,0.f,0.f};
        if (k0 + lc < K){
            xv = *(const float4*)(X + (size_t)(tok0 + lr) * ldX + k0 + lc);
            wv = *(const float4*)(W + (size_t)(o0 + lr) * K + k0 + lc);
        }
        __syncthreads();
        Xs[lc+0][lr] = xv.x; Xs[lc+1][lr] = xv.y; Xs[lc+2][lr] = xv.z; Xs[lc+3][lr] = xv.w;
        Ws[lc+0][lr] = wv.x; Ws[lc+1][lr] = wv.y; Ws[lc+2][lr] = wv.z; Ws[lc+3][lr] = wv.w;
        __syncthreads();
        #pragma unroll
        for (int kk = 0; kk < 16; kk++){
            float4 a = *(const float4*)&Xs[kk][ty * 4];
            float4 w = *(const float4*)&Ws[kk][tx * 4];
            float av[4] = {a.x, a.y, a.z, a.w};
            float wv2[4] = {w.x, w.y, w.z, w.w};
            #pragma unroll
            for (int i = 0; i < 4; i++)
                #pragma unroll
                for (int j = 0; j < 4; j++)
                    acc[i][j] += av[i] * wv2[j];
        }
    }
    #pragma unroll
    for (int i = 0; i < 4; i++){
        _Float16* zr = Zd + (size_t)(tok0 + ty * 4 + i) * G4 + o0 + tx * 4;
        #pragma unroll
        for (int j = 0; j < 4; j++) zr[j] = (_Float16)acc[i][j];
    }
}

// ---------- 4) LSTM: 4 blocks per chain; weights in 40 NAMED uint4 regs (SROA-proof);
// exchange via all-relaxed atomics + explicit vmcnt drain (no L2 invalidate/writeback). ----------
__global__ __launch_bounds__(512, 2) void k_lstm2(const _Float16* __restrict__ Zh, const UINT* __restrict__ wpk,
                                                  float* __restrict__ Xout, int layer,
                                                  UINT* __restrict__ Hbuf, UINT* __restrict__ flags){
    int bidx = blockIdx.x;
    int chain = bidx & 63;          // bi*2 + dir
    int slice = bidx >> 6;          // 0..3
    int bi = chain >> 1, dir = chain & 1;
    int tid = threadIdx.x;
    int ksl = tid / 100;            // 0..5 (5 = inactive tail)
    int j   = tid - ksl * 100;      // 0..99
    bool act = (tid < 500);
    int gj = slice * JS + j;

    const uint4* wp4 = (const uint4*)wpk + (size_t)(layer * 2 + dir) * 80000;
    const _Float16* Zd = Zh + (size_t)dir * TOKENS * G4 + (size_t)bi * SEQ * G4;
    float* Xo = Xout + (size_t)bi * SEQ * 800 + dir * HID;

    // resident weights: 40 NAMED uint4 = 160 VGPRs (clamped addr for inactive tail threads)
    int kb  = act ? ksl * KP : 0;
    int gjc = act ? gj : slice * JS;
#define LOADW(n) uint4 w##n = wp4[(size_t)(kb + n) * 400 + gjc]
    LOADW(0);  LOADW(1);  LOADW(2);  LOADW(3);  LOADW(4);  LOADW(5);  LOADW(6);  LOADW(7);
    LOADW(8);  LOADW(9);  LOADW(10); LOADW(11); LOADW(12); LOADW(13); LOADW(14); LOADW(15);
    LOADW(16); LOADW(17); LOADW(18); LOADW(19); LOADW(20); LOADW(21); LOADW(22); LOADW(23);
    LOADW(24); LOADW(25); LOADW(26); LOADW(27); LOADW(28); LOADW(29); LOADW(30); LOADW(31);
    LOADW(32); LOADW(33); LOADW(34); LOADW(35); LOADW(36); LOADW(37); LOADW(38); LOADW(39);
#undef LOADW

    __shared__ __align__(16) UINT hu32[200];        // full h as f16 pairs
    __shared__ float psum[4][KS][JS];               // 8 KB partials
    __shared__ _Float16 hnew[JS];

    for (int i = tid; i < 200; i += 512) hu32[i] = 0u;
    __syncthreads();

    UINT* myflag   = flags + chain * 4 + slice;
    UINT* slotbase = Hbuf + (size_t)chain * 2 * 200;
    const UINT eb = (UINT)(layer * SEQ);
    float c = 0.f;

    for (int s = 0; s < SEQ; s++){
        int t = dir ? (SEQ - 1 - s) : s;
        const _Float16* zr = Zd + (size_t)t * G4;
        float zi = 0.f, zf = 0.f, zg = 0.f, zo = 0.f;
        if (tid < JS){   // issue gate-bias loads early; latency hides under the dot chain
            zi = (float)zr[gj];         zf = (float)zr[HID + gj];
            zg = (float)zr[2*HID + gj]; zo = (float)zr[3*HID + gj];
        }
        // 1) dot partials: weights from named VGPRs, h broadcast from LDS (fully static chain)
        if (act){
            float a0 = 0.f, a1 = 0.f, a2 = 0.f, a3 = 0.f;
            const uint4* hb4 = (const uint4*)(hu32 + kb);   // kb = ksl*40 -> 160B aligned
#define DOTQ(n, hv) { a0 = dot2f(w##n.x, hv, a0); a1 = dot2f(w##n.y, hv, a1); \
                      a2 = dot2f(w##n.z, hv, a2); a3 = dot2f(w##n.w, hv, a3); }
#define DOT16(g, n0, n1, n2, n3) { uint4 hh = hb4[g]; \
            DOTQ(n0, hh.x); DOTQ(n1, hh.y); DOTQ(n2, hh.z); DOTQ(n3, hh.w); }
            DOT16(0,  0,  1,  2,  3);
            DOT16(1,  4,  5,  6,  7);
            DOT16(2,  8,  9, 10, 11);
            DOT16(3, 12, 13, 14, 15);
            DOT16(4, 16, 17, 18, 19);
            DOT16(5, 20, 21, 22, 23);
            DOT16(6, 24, 25, 26, 27);
            DOT16(7, 28, 29, 30, 31);
            DOT16(8, 32, 33, 34, 35);
            DOT16(9, 36, 37, 38, 39);
#undef DOT16
#undef DOTQ
            psum[0][ksl][j] = a0; psum[1][ksl][j] = a1;
            psum[2][ksl][j] = a2; psum[3][ksl][j] = a3;
        }
        __syncthreads();
        // 2) reduce + cell update (tid<100 <=> ksl==0, j=tid)
        if (tid < JS){
            float ai = zi, af = zf, ag = zg, ao = zo;
            #pragma unroll
            for (int k = 0; k < KS; k++){
                ai += psum[0][k][tid]; af += psum[1][k][tid];
                ag += psum[2][k][tid]; ao += psum[3][k][tid];
            }
            float ig = sigm(ai), fg = sigm(af), gg = tanh_f(ag), og = sigm(ao);
            c = fg * c + ig * gg;
            float hval = og * tanh_f(c);
            Xo[(size_t)t * 800 + gj] = hval;
            hnew[tid] = (_Float16)hval;
        }
        __syncthreads();
        // 3) publish own slice: relaxed data stores -> vmcnt(0) drain -> barrier -> relaxed flag
        UINT epoch = eb + (UINT)s + 1u;
        UINT* slot = slotbase + (s & 1) * 200;
        if (tid < 50){
            UINT pk = (UINT)__builtin_bit_cast(USHORT, hnew[2*tid])
                    | ((UINT)__builtin_bit_cast(USHORT, hnew[2*tid+1]) << 16);
            hu32[slice * 50 + tid] = pk;                     // own slice locally
            __hip_atomic_store(slot + slice * 50 + tid, pk, __ATOMIC_RELAXED, __HIP_MEMORY_SCOPE_AGENT);
            asm volatile("s_waitcnt vmcnt(0)" ::: "memory"); // data at coherence point
        }
        __syncthreads();
        if (tid == 0){
            __hip_atomic_store(myflag, epoch, __ATOMIC_RELAXED, __HIP_MEMORY_SCOPE_AGENT);
        } else if (tid >= 64 && tid < 67){
            int p = tid - 64;
            int ps = p + (p >= slice);
            while (__hip_atomic_load(flags + chain * 4 + ps, __ATOMIC_RELAXED, __HIP_MEMORY_SCOPE_AGENT) < epoch)
                __builtin_amdgcn_s_sleep(1);
        }
        __syncthreads();
        // 4) fetch peer slices into hu32 (relaxed atomics read the coherence point)
        if (tid < 150){
            int p = tid / 50, i = tid - p * 50;
            int ps = p + (p >= slice);
            UINT v = __hip_atomic_load(slot + ps * 50 + i, __ATOMIC_RELAXED, __HIP_MEMORY_SCOPE_AGENT);
            hu32[ps * 50 + i] = v;
        }
        __syncthreads();
    }
}

// ---------- 5) MLPs -> transposed l1T/r1T [feature][row] ----------
__global__ __launch_bounds__(256) void k_mlp(const float* __restrict__ X,
                                             const float* __restrict__ Wl, const float* __restrict__ bl,
                                             const float* __restrict__ Wr, const float* __restrict__ br,
                                             float* __restrict__ l1T, float* __restrict__ r1T){
    int r = blockIdx.x;            // 0..4063
    int b = r / NPOS, x = r % NPOS;
    __shared__ float feat[800];
    const float* xrow = X + (size_t)(b * SEQ + x) * 800;
    int tid = threadIdx.x;
    for (int k = tid; k < 800; k += 256) feat[k] = (k < 400) ? xrow[k] : xrow[800 + k];
    __syncthreads();
    if (tid < 200){
        int isl = (tid < 100);
        int m = isl ? tid : tid - 100;
        const float* W = (isl ? Wl : Wr) + (size_t)m * 800;
        float acc = (isl ? bl : br)[m];
        for (int k = 0; k < 800; k += 4){
            float4 w4 = *(const float4*)(W + k);
            acc += w4.x * feat[k]   + w4.y * feat[k+1]
                 + w4.z * feat[k+2] + w4.w * feat[k+3];
        }
        float v = acc > 0.f ? acc : 0.1f * acc;
        (isl ? l1T : r1T)[(size_t)m * LD1T + r] = v;
    } else if (tid == 200){ l1T[(size_t)100 * LD1T + r] = 1.0f; }
    else if (tid == 201){ r1T[(size_t)100 * LD1T + r] = 1.0f; }
}

// ---------- 6a) biaffine -> T[bb][o][x][ypad128], coalesced stores ----------
__global__ __launch_bounds__(256) void k_biaffineT(const float* __restrict__ l1T, const float* __restrict__ r1T,
                                                   const float* __restrict__ BW, float* __restrict__ T, int b0){
    int o = blockIdx.x, bb = blockIdx.y, b = b0 + bb;
    extern __shared__ float sm[];
    float* Wl = sm;                  // 101*104
    float* Rt = sm + 101 * 104;      // 101*128
    float* Vt = Rt + 101 * 128;      // 101*128
    float* Lt = sm;                  // reuse after stage A
    int tid = threadIdx.x;
    const float* wo = BW + (size_t)o * 10201;
    for (int idx = tid; idx < 10201; idx += 256){
        int i = idx / 101, jj = idx % 101;
        Wl[i * 104 + jj] = wo[idx];
    }
    const float* rb = r1T + b * NPOS;
    for (int idx = tid; idx < 101 * 128; idx += 256){
        int jj = idx >> 7, y = idx & 127;
        Rt[idx] = (y < NPOS) ? rb[(size_t)jj * LD1T + y] : 0.f;
    }
    __syncthreads();
    {   // stage A
        int ty = tid & 31, ti = tid >> 5;
        for (int i = ti; i < 101; i += 8){
            float a0 = 0.f, a1 = 0.f, a2 = 0.f, a3 = 0.f;
            const float* wrow = Wl + i * 104;
            #pragma unroll 2
            for (int jj = 0; jj < 101; jj++){
                float w = wrow[jj];
                float4 r4 = *(const float4*)(Rt + jj * 128 + ty * 4);
                a0 += w * r4.x; a1 += w * r4.y; a2 += w * r4.z; a3 += w * r4.w;
            }
            float4 v; v.x = a0; v.y = a1; v.z = a2; v.w = a3;
            *(float4*)(Vt + i * 128 + ty * 4) = v;
        }
    }
    __syncthreads();
    const float* lb = l1T + b * NPOS;
    for (int idx = tid; idx < 101 * 128; idx += 256){
        int ii = idx >> 7, x = idx & 127;
        Lt[idx] = (x < NPOS) ? lb[(size_t)ii * LD1T + x] : 0.f;
    }
    __syncthreads();
    {   // stage B: lanes vary y -> coalesced T stores
        int ty = tid & 31;
        int tx8 = tid >> 5;
        float* tb = T + (size_t)(bb * 128 + o) * 127 * 128;
        for (int xp = 0; xp < 4; xp++){
            int x0 = (tx8 + 8 * xp) * 4;
            float accm[4][4] = {};
            for (int i = 0; i < 101; i++){
                float4 l4 = *(const float4*)(Lt + i * 128 + x0);
                float4 v4 = *(const float4*)(Vt + i * 128 + ty * 4);
                float lv[4] = {l4.x, l4.y, l4.z, l4.w};
                float vv[4] = {v4.x, v4.y, v4.z, v4.w};
                #pragma unroll
                for (int xx = 0; xx < 4; xx++)
                    #pragma unroll
                    for (int yy = 0; yy < 4; yy++)
                        accm[xx][yy] += lv[xx] * vv[yy];
            }
            #pragma unroll
            for (int xx = 0; xx < 4; xx++){
                int x = x0 + xx;
                if (x >= NPOS) continue;
                float4 wv; wv.x = accm[xx][0]; wv.y = accm[xx][1]; wv.z = accm[xx][2]; wv.w = accm[xx][3];
                *(float4*)(tb + (size_t)x * 128 + ty * 4) = wv;
            }
        }
    }
}

// ---------- 6b) transpose T[bb][o][x][ypad] -> out[b][x][y][o] ----------
__global__ __launch_bounds__(256) void k_transpose(const float* __restrict__ T, float* __restrict__ out, int b0){
    int x = blockIdx.x, bb = blockIdx.y, b = b0 + bb;
    extern __shared__ float ts[];    // [o][129]
    int tid = threadIdx.x;
    for (int idx = tid; idx < 128 * 32; idx += 256){
        int o = idx >> 5, y4 = idx & 31;
        float4 v = *(const float4*)(T + ((size_t)(bb * 128 + o) * 127 + x) * 128 + y4 * 4);
        float* d = ts + o * 129 + y4 * 4;
        d[0] = v.x; d[1] = v.y; d[2] = v.z; d[3] = v.w;
    }
    __syncthreads();
    float* ob = out + ((size_t)(b * NPOS + x)) * NPOS * 128;
    for (int idx = tid; idx < NPOS * 32; idx += 256){
        int y = idx >> 5, o4 = idx & 31;
        float4 w;
        w.x = ts[(o4 * 4 + 0) * 129 + y];
        w.y = ts[(o4 * 4 + 1) * 129 + y];
        w.z = ts[(o4 * 4 + 2) * 129 + y];
        w.w = ts[(o4 * 4 + 3) * 129 + y];
        *(float4*)(ob + (size_t)y * 128 + o4 * 4) = w;
    }
}

extern "C" void kernel_launch(void* const* d_in, const int* in_sizes, int n_in,
                              void* d_out, int out_size, void* d_ws, size_t ws_size,
                              hipStream_t stream) {
    const int* words = (const int*)d_in[0];
    const int* tags  = (const int*)d_in[1];
    const float* wemb = (const float*)d_in[2];
    const float* temb = (const float*)d_in[3];
    const float* wih[3] = {(const float*)d_in[4], (const float*)d_in[5], (const float*)d_in[6]};
    const float* whh  = (const float*)d_in[7];
    const float* bias = (const float*)d_in[8];
    const float* mlW = (const float*)d_in[9];
    const float* mlb = (const float*)d_in[10];
    const float* mrW = (const float*)d_in[11];
    const float* mrb = (const float*)d_in[12];
    const float* bw  = (const float*)d_in[13];
    float* out = (float*)d_out;

    // workspace layout (bytes):
    //   [0 .. 13,107,200)            x f32 (reused as T after k_mlp)
    //   [13,107,200 .. 39,321,600)   Zh f16
    //   [39,321,600 .. 47,001,600)   wpk u32 (l1T/r1T overlay after last LSTM)
    //   [47,001,600 .. +103,424)     Hbuf (102,400 B) + flags (1,024 B)  [fallback: tail of out]
    char* base = (char*)d_ws;
    float*     x   = (float*)base;
    _Float16*  Zh  = (_Float16*)(base + 13107200);
    UINT*      wpk = (UINT*)(base + 13107200 + 26214400);
    float*     l1T = (float*)(base + 39321600);
    float*     r1T = l1T + (size_t)104 * LD1T;
    float*     T   = (float*)base;

    const size_t SYNC_BYTES = 102400 + 1024;
    char* sync_base;
    if (ws_size >= (size_t)47001600 + SYNC_BYTES){
        sync_base = base + 47001600;
    } else {
        size_t off = ((size_t)out_size - SYNC_BYTES) & ~(size_t)255;
        sync_base = (char*)d_out + off;
    }
    UINT* Hbuf  = (UINT*)sync_base;           // 64 chains * 2 parity * 200 u32
    UINT* flags = Hbuf + 51200;               // 256 u32

    (void)hipMemsetAsync(flags, 0, 1024, stream);
    k_convert_whh<<<1875, 256, 0, stream>>>(whh, wpk);
    k_embed<<<TOKENS, 64, 0, stream>>>(words, tags, wemb, temb, x);

    for (int l = 0; l < 3; l++){
        int K = l ? 800 : 200;
        k_gemm_ih<<<dim3(25, 64, 2), 256, 0, stream>>>(x, K, K, wih[l], bias + l * 2 * G4, Zh);
        k_lstm2<<<256, 512, 0, stream>>>(Zh, wpk, x, l, Hbuf, flags);
    }
    k_mlp<<<NROW, 256, 0, stream>>>(x, mlW, mlb, mrW, mrb, l1T, r1T);

    (void)hipFuncSetAttribute((const void*)k_biaffineT, hipFuncAttributeMaxDynamicSharedMemorySize, 145440);
    (void)hipFuncSetAttribute((const void*)k_transpose, hipFuncAttributeMaxDynamicSharedMemorySize, 66048);
    for (int c = 0; c < NB / CHUNK_B; c++){
        k_biaffineT<<<dim3(128, CHUNK_B), 256, 145440, stream>>>(l1T, r1T, bw, T, c * CHUNK_B);
        k_transpose<<<dim3(NPOS, CHUNK_B), 256, 66048, stream>>>(T, out, c * CHUNK_B);
    }
}